// Round 1
// 777.855 us; speedup vs baseline: 1.4320x; 1.4320x over previous
//
#include <hip/hip_runtime.h>

#define BB 2
#define LL 2048
#define DD 1024
#define HH 16
#define DHD 64

typedef __attribute__((ext_vector_type(8))) short bf16x8;
typedef __attribute__((ext_vector_type(4))) float f32x4;
typedef unsigned long long ull;
typedef unsigned short u16;
typedef unsigned int u32;

#define MFMA16(a, b, c) __builtin_amdgcn_mfma_f32_16x16x32_bf16((a), (b), (c), 0, 0, 0)

__device__ __forceinline__ u16 f2bf(float f) {
    union { float f; u32 u; } c; c.f = f;
    u32 r = 0x7FFFu + ((c.u >> 16) & 1u);
    return (u16)((c.u + r) >> 16);
}
__device__ __forceinline__ ull pack4(float x, float y, float z, float w) {
    return (ull)f2bf(x) | ((ull)f2bf(y) << 16) | ((ull)f2bf(z) << 32) | ((ull)f2bf(w) << 48);
}

// Byte offset of element (row, col) in a [64][64] bf16 LDS tile (128 B rows),
// XOR-swizzled in 16 B chunks: chunk' = chunk ^ ((row ^ (row>>3)) & 7).
// Involution -> same transform on write-source and read side.
__device__ __forceinline__ int swz(int row, int col) {
    int key = (row ^ (row >> 3)) & 7;
    return (row << 7) + ((col << 1) ^ (key << 4));
}

__device__ __forceinline__ void gl_lds16(const void* g, void* l) {
    __builtin_amdgcn_global_load_lds(
        (const __attribute__((address_space(1))) u32*)g,
        (__attribute__((address_space(3))) u32*)l, 16, 0, 0);
}

// ---------------- converters ----------------
__global__ __launch_bounds__(256) void to_bf16(const float* __restrict__ in,
                                               u16* __restrict__ out, int n4) {
    int i = blockIdx.x * 256 + threadIdx.x;
    if (i < n4) {
        float4 f = ((const float4*)in)[i];
        ((ull*)out)[i] = pack4(f.x, f.y, f.z, f.w);
    }
}

// out[cols][rows] (bf16) = transpose of in[rows][cols] (fp32)
__global__ __launch_bounds__(256) void transpose_bf16(const float* __restrict__ in,
                                                      u16* __restrict__ out,
                                                      int rows, int cols) {
    __shared__ float t[32][33];
    int bx = blockIdx.x * 32;           // col base
    int by = blockIdx.y * 32;           // row base
    int tx = threadIdx.x & 31, ty = threadIdx.x >> 5;
#pragma unroll
    for (int i = 0; i < 4; ++i)
        t[ty + i * 8][tx] = in[(size_t)(by + ty + i * 8) * cols + bx + tx];
    __syncthreads();
#pragma unroll
    for (int i = 0; i < 4; ++i)
        out[(size_t)(bx + ty + i * 8) * rows + by + tx] = f2bf(t[tx][ty + i * 8]);
}

// ---------------- bf16 GEMM, B pre-transposed: C[m][n] = sum_k A[m][k]*Bt[n][k]
// 128x128 tile, BK=64, 256 threads / 4 waves, each wave 64x64 (4x4 16x16 frags),
// global_load_lds dwordx4 staging (m97 structure).
template <int BF16OUT>
__global__ __launch_bounds__(256) void gemm_bt(
    const u16* __restrict__ A, const u16* __restrict__ Bt, void* __restrict__ Cout,
    int M, int N, int K)
{
    __shared__ u16 As[128 * 64];
    __shared__ u16 Bs[128 * 64];
    const int tid  = threadIdx.x;
    const int lane = tid & 63, wave = tid >> 6;
    const int l15  = lane & 15, quad = lane >> 4;
    const int m0 = blockIdx.y * 128, n0 = blockIdx.x * 128;
    const int wm = (wave >> 1) * 64, wn = (wave & 1) * 64;

    f32x4 acc[4][4];
#pragma unroll
    for (int i = 0; i < 4; ++i)
#pragma unroll
        for (int j = 0; j < 4; ++j) acc[i][j] = (f32x4){0.f, 0.f, 0.f, 0.f};

    for (int k0 = 0; k0 < K; k0 += 64) {
#pragma unroll
        for (int i = 0; i < 4; ++i) {
            int ci  = (i * 4 + wave) * 64 + lane;   // 0..1023 chunks of 16 B
            int row = ci >> 3, c = (ci & 7) * 8;
            gl_lds16(&A[(size_t)(m0 + row) * K + k0 + c],
                     (char*)As + (i * 4 + wave) * 1024);
            gl_lds16(&Bt[(size_t)(n0 + row) * K + k0 + c],
                     (char*)Bs + (i * 4 + wave) * 1024);
        }
        __syncthreads();
#pragma unroll
        for (int ks = 0; ks < 64; ks += 32) {
            bf16x8 a[4], b[4];
#pragma unroll
            for (int i = 0; i < 4; ++i)
                a[i] = *(const bf16x8*)&As[(wm + i * 16 + l15) * 64 + ks + quad * 8];
#pragma unroll
            for (int j = 0; j < 4; ++j)
                b[j] = *(const bf16x8*)&Bs[(wn + j * 16 + l15) * 64 + ks + quad * 8];
#pragma unroll
            for (int i = 0; i < 4; ++i)
#pragma unroll
                for (int j = 0; j < 4; ++j)
                    acc[i][j] = MFMA16(a[i], b[j], acc[i][j]);
        }
        __syncthreads();
    }
#pragma unroll
    for (int i = 0; i < 4; ++i)
#pragma unroll
        for (int j = 0; j < 4; ++j)
#pragma unroll
            for (int r = 0; r < 4; ++r) {
                int row = m0 + wm + i * 16 + quad * 4 + r;
                int col = n0 + wn + j * 16 + l15;
                if (BF16OUT)
                    ((u16*)Cout)[(size_t)row * N + col] = f2bf(acc[i][j][r]);
                else
                    ((float*)Cout)[(size_t)row * N + col] = acc[i][j][r];
            }
}

// ---------------- attention v2: bf16 qkv in, align fp32 + ctx bf16 out ----------------
// One block per (b, h, 64-row Q tile). 256 threads / 4 waves; two-pass softmax.
// LDS 40 KB: [Qs|Pa 8K][Ks dbuf 16K][Vt dbuf 16K] -> 4 blocks/CU.
__global__ __launch_bounds__(256, 4) void attn_v2(
    const u16* __restrict__ qkv,     // [B*L][3*D] bf16
    const float* __restrict__ bias,  // [B][L]
    float* __restrict__ align_out,   // [B*H][Lk][Lq] fp32
    u16* __restrict__ ctx_out)       // [B*L][D] bf16
{
    __shared__ u16 smem[20480];
    u16* QP = smem;            // 4096 u16: Qs, later reused as Pa
    u16* Ks = smem + 4096;     // 2 x 4096 u16
    u16* Vt = smem + 12288;    // 2 x 4096 u16

    const int tid  = threadIdx.x;
    const int lane = tid & 63, wave = tid >> 6;
    const int l15  = lane & 15, quad = lane >> 4;
    const int strip = wave * 16;
    // XCD-aware swizzle: 1024 blocks -> 8 chunks of 128 so one head's 32 q-tiles
    // share an XCD L2.
    const int bid = ((blockIdx.x & 7) << 7) | (blockIdx.x >> 3);
    const int bh = bid >> 5, qt = bid & 31;
    const int b  = bh >> 4, h = bh & 15;
    const int q0 = qt * 64;
    const u16* qbase = qkv + (size_t)b * LL * (3 * DD);
    const float scale = 0.125f;

    // ---- stage Q tile (swizzled source -> linear LDS via global_load_lds) ----
#pragma unroll
    for (int i = 0; i < 2; ++i) {
        int ci  = (i * 4 + wave) * 64 + lane;      // 0..511
        int row = ci >> 3, c = ci & 7;
        int cs  = c ^ ((row ^ (row >> 3)) & 7);
        gl_lds16(&qbase[(size_t)(q0 + row) * (3 * DD) + h * DHD + cs * 8],
                 (char*)QP + (i * 4 + wave) * 1024);
    }
    __syncthreads();
    bf16x8 aq0 = *(const bf16x8*)((const char*)QP + swz(strip + l15, quad * 8));
    bf16x8 aq1 = *(const bf16x8*)((const char*)QP + swz(strip + l15, 32 + quad * 8));

    auto stageK = [&](int kt, int bi) {
#pragma unroll
        for (int i = 0; i < 2; ++i) {
            int ci  = (i * 4 + wave) * 64 + lane;
            int row = ci >> 3, c = ci & 7;
            int cs  = c ^ ((row ^ (row >> 3)) & 7);
            gl_lds16(&qbase[(size_t)(kt * 64 + row) * (3 * DD) + DD + h * DHD + cs * 8],
                     (char*)(Ks + bi * 4096) + (i * 4 + wave) * 1024);
        }
    };

    float m_[4], l_[4];
#pragma unroll
    for (int r = 0; r < 4; ++r) { m_[r] = -1e30f; l_[r] = 0.f; }

    // ---------- pass 1: online row max + sumexp ----------
    stageK(0, 0);
    __syncthreads();
    for (int kt = 0; kt < 32; ++kt) {
        const int cur = kt & 1;
        if (kt < 31) stageK(kt + 1, cur ^ 1);
        const char* kb = (const char*)(Ks + cur * 4096);
        float Sv[4][4];
#pragma unroll
        for (int j = 0; j < 4; ++j) {
            f32x4 s = (f32x4){0.f, 0.f, 0.f, 0.f};
            bf16x8 bk0 = *(const bf16x8*)(kb + swz(j * 16 + l15, quad * 8));
            bf16x8 bk1 = *(const bf16x8*)(kb + swz(j * 16 + l15, 32 + quad * 8));
            s = MFMA16(aq0, bk0, s);
            s = MFMA16(aq1, bk1, s);
            float bv = bias[b * LL + kt * 64 + j * 16 + l15];
#pragma unroll
            for (int r = 0; r < 4; ++r) Sv[j][r] = s[r] * scale + bv;
        }
#pragma unroll
        for (int r = 0; r < 4; ++r) {
            float tm = fmaxf(fmaxf(Sv[0][r], Sv[1][r]), fmaxf(Sv[2][r], Sv[3][r]));
#pragma unroll
            for (int off = 1; off < 16; off <<= 1) tm = fmaxf(tm, __shfl_xor(tm, off));
            float ts = 0.f;
#pragma unroll
            for (int j = 0; j < 4; ++j) ts += __expf(Sv[j][r] - tm);
#pragma unroll
            for (int off = 1; off < 16; off <<= 1) ts += __shfl_xor(ts, off);
            float mn = fmaxf(m_[r], tm);
            l_[r] = l_[r] * __expf(m_[r] - mn) + ts * __expf(tm - mn);
            m_[r] = mn;
        }
        __syncthreads();
    }

    float rl[4];
#pragma unroll
    for (int r = 0; r < 4; ++r) rl[r] = 1.f / l_[r];
    f32x4 ctx[4];
#pragma unroll
    for (int j = 0; j < 4; ++j) ctx[j] = (f32x4){0.f, 0.f, 0.f, 0.f};

    u16* Pa = QP;  // reuse Q LDS as P A-fragment buffer

    // V reg-staging (T14 split: load early, ds_write late)
    const int vr0 = tid >> 3, vs0 = tid & 7;
    const int vr1 = (tid + 256) >> 3, vs1 = (tid + 256) & 7;
    const u16* vbase = qbase + 2 * DD + h * DHD;
    bf16x8 vv0, vv1;
    auto loadV = [&](int kt) {
        vv0 = *(const bf16x8*)&vbase[(size_t)(kt * 64 + vr0) * (3 * DD) + vs0 * 8];
        vv1 = *(const bf16x8*)&vbase[(size_t)(kt * 64 + vr1) * (3 * DD) + vs1 * 8];
    };
    auto writeV = [&](int bi) {
        u16* vb = Vt + bi * 4096;
#pragma unroll
        for (int e = 0; e < 8; ++e)
            *(u16*)((char*)vb + swz(vs0 * 8 + e, vr0)) = (u16)vv0[e];
#pragma unroll
        for (int e = 0; e < 8; ++e)
            *(u16*)((char*)vb + swz(vs1 * 8 + e, vr1)) = (u16)vv1[e];
    };

    // ---------- pass 2: recompute S, write align, accumulate context ----------
    stageK(0, 0);
    loadV(0);
    writeV(0);
    __syncthreads();
    for (int kt = 0; kt < 32; ++kt) {
        const int cur = kt & 1;
        if (kt < 31) { stageK(kt + 1, cur ^ 1); loadV(kt + 1); }

        const char* kb = (const char*)(Ks + cur * 4096);
        float Sv[4][4];
#pragma unroll
        for (int j = 0; j < 4; ++j) {
            f32x4 s = (f32x4){0.f, 0.f, 0.f, 0.f};
            bf16x8 bk0 = *(const bf16x8*)(kb + swz(j * 16 + l15, quad * 8));
            bf16x8 bk1 = *(const bf16x8*)(kb + swz(j * 16 + l15, 32 + quad * 8));
            s = MFMA16(aq0, bk0, s);
            s = MFMA16(aq1, bk1, s);
            float bv = bias[b * LL + kt * 64 + j * 16 + l15];
#pragma unroll
            for (int r = 0; r < 4; ++r) Sv[j][r] = s[r] * scale + bv;
        }
        // P in regs -> align direct dwordx4 store + Pa bf16 LDS
#pragma unroll
        for (int j = 0; j < 4; ++j) {
            f32x4 pv;
#pragma unroll
            for (int r = 0; r < 4; ++r) {
                float p = __expf(Sv[j][r] - m_[r]) * rl[r];
                pv[r] = p;
                *(u16*)((char*)Pa + swz(strip + quad * 4 + r, j * 16 + l15)) = f2bf(p);
            }
            *(f32x4*)&align_out[((size_t)bh * LL + kt * 64 + j * 16 + l15) * LL +
                                q0 + strip + quad * 4] = pv;
        }
        __syncthreads();   // Pa visible (Vt[cur] visible since prev barrier)
#pragma unroll
        for (int ks = 0; ks < 64; ks += 32) {
            bf16x8 ap = *(const bf16x8*)((const char*)Pa + swz(strip + l15, ks + quad * 8));
            const char* vb = (const char*)(Vt + cur * 4096);
#pragma unroll
            for (int j = 0; j < 4; ++j) {
                bf16x8 bvv = *(const bf16x8*)(vb + swz(j * 16 + l15, ks + quad * 8));
                ctx[j] = MFMA16(ap, bvv, ctx[j]);
            }
        }
        if (kt < 31) writeV(cur ^ 1);   // write next V while others still in PV(cur)
        __syncthreads();
    }

    // ctx -> bf16 [B*L][D]
#pragma unroll
    for (int j = 0; j < 4; ++j)
#pragma unroll
        for (int r = 0; r < 4; ++r) {
            int ql = strip + quad * 4 + r;
            int dv = j * 16 + l15;
            ctx_out[(size_t)(b * LL + q0 + ql) * DD + h * DHD + dv] = f2bf(ctx[j][r]);
        }
}

extern "C" void kernel_launch(void* const* d_in, const int* in_sizes, int n_in,
                              void* d_out, int out_size, void* d_ws, size_t ws_size,
                              hipStream_t stream) {
    const float* queries = (const float*)d_in[0];
    const float* bias    = (const float*)d_in[1];
    const float* w_qkv   = (const float*)d_in[2];
    const float* w_o     = (const float*)d_in[3];

    float* out_p   = (float*)d_out;
    float* align_p = out_p + (size_t)BB * LL * DD;

    u16* qbf   = (u16*)d_ws;                          // [4096][1024] bf16
    u16* wqkT  = qbf + (size_t)BB * LL * DD;          // [3072][1024] bf16 (w_qkv^T)
    u16* woT   = wqkT + (size_t)(3 * DD) * DD;        // [1024][1024] bf16 (w_o^T)
    u16* qkvbf = woT + (size_t)DD * DD;               // [4096][3072] bf16
    u16* ctxbf = qkvbf + (size_t)BB * LL * 3 * DD;    // [4096][1024] bf16

    // 0) converts / transposes (weights are tiny; ~15 us total)
    to_bf16<<<(BB * LL * DD / 4 + 255) / 256, 256, 0, stream>>>(queries, qbf, BB * LL * DD / 4);
    transpose_bf16<<<dim3(3 * DD / 32, DD / 32), 256, 0, stream>>>(w_qkv, wqkT, DD, 3 * DD);
    transpose_bf16<<<dim3(DD / 32, DD / 32), 256, 0, stream>>>(w_o, woT, DD, DD);

    // 1) qkv = queries @ w_qkv   (M=4096, N=3072, K=1024) -> bf16
    gemm_bt<1><<<dim3(3 * DD / 128, BB * LL / 128), 256, 0, stream>>>(
        qbf, wqkT, qkvbf, BB * LL, 3 * DD, DD);

    // 2) attention: align (fp32) + ctx (bf16)
    attn_v2<<<dim3(BB * HH * (LL / 64)), 256, 0, stream>>>(qkvbf, bias, align_p, ctxbf);

    // 3) out = ctx @ w_o   (M=4096, N=1024, K=1024) -> fp32
    gemm_bt<0><<<dim3(DD / 128, BB * LL / 128), 256, 0, stream>>>(
        ctxbf, woT, out_p, BB * LL, DD, DD);
}

// Round 2
// 746.251 us; speedup vs baseline: 1.4927x; 1.0423x over previous
//
#include <hip/hip_runtime.h>

#define BB 2
#define LL 2048
#define DD 1024
#define HH 16
#define DHD 64

typedef __attribute__((ext_vector_type(8))) short bf16x8;
typedef __attribute__((ext_vector_type(4))) float f32x4;
typedef unsigned long long ull;
typedef unsigned short u16;
typedef unsigned int u32;

#define MFMA16(a, b, c) __builtin_amdgcn_mfma_f32_16x16x32_bf16((a), (b), (c), 0, 0, 0)

__device__ __forceinline__ u16 f2bf(float f) {
    union { float f; u32 u; } c; c.f = f;
    u32 r = 0x7FFFu + ((c.u >> 16) & 1u);
    return (u16)((c.u + r) >> 16);
}
__device__ __forceinline__ ull pack4(float x, float y, float z, float w) {
    return (ull)f2bf(x) | ((ull)f2bf(y) << 16) | ((ull)f2bf(z) << 32) | ((ull)f2bf(w) << 48);
}

// Byte offset of element (row, col) in a [R][64] bf16 LDS tile (128 B rows),
// XOR-swizzled in 16 B chunks: chunk' = chunk ^ ((row ^ (row>>3)) & 7).
__device__ __forceinline__ int swz(int row, int col) {
    int key = (row ^ (row >> 3)) & 7;
    return (row << 7) + ((col << 1) ^ (key << 4));
}

__device__ __forceinline__ void gl_lds16(const void* g, void* l) {
    __builtin_amdgcn_global_load_lds(
        (const __attribute__((address_space(1))) u32*)g,
        (__attribute__((address_space(3))) u32*)l, 16, 0, 0);
}

// ---------------- converters ----------------
__global__ __launch_bounds__(256) void to_bf16(const float* __restrict__ in,
                                               u16* __restrict__ out, int n4) {
    int i = blockIdx.x * 256 + threadIdx.x;
    if (i < n4) {
        float4 f = ((const float4*)in)[i];
        ((ull*)out)[i] = pack4(f.x, f.y, f.z, f.w);
    }
}

__global__ __launch_bounds__(256) void transpose_bf16(const float* __restrict__ in,
                                                      u16* __restrict__ out,
                                                      int rows, int cols) {
    __shared__ float t[32][33];
    int bx = blockIdx.x * 32;
    int by = blockIdx.y * 32;
    int tx = threadIdx.x & 31, ty = threadIdx.x >> 5;
#pragma unroll
    for (int i = 0; i < 4; ++i)
        t[ty + i * 8][tx] = in[(size_t)(by + ty + i * 8) * cols + bx + tx];
    __syncthreads();
#pragma unroll
    for (int i = 0; i < 4; ++i)
        out[(size_t)(bx + ty + i * 8) * rows + by + tx] = f2bf(t[tx][ty + i * 8]);
}

// ---------------- bf16 GEMM, B pre-transposed (m97 structure) ----------------
template <int BF16OUT>
__global__ __launch_bounds__(256) void gemm_bt(
    const u16* __restrict__ A, const u16* __restrict__ Bt, void* __restrict__ Cout,
    int M, int N, int K)
{
    __shared__ u16 As[128 * 64];
    __shared__ u16 Bs[128 * 64];
    const int tid  = threadIdx.x;
    const int lane = tid & 63, wave = tid >> 6;
    const int l15  = lane & 15, quad = lane >> 4;
    const int m0 = blockIdx.y * 128, n0 = blockIdx.x * 128;
    const int wm = (wave >> 1) * 64, wn = (wave & 1) * 64;

    f32x4 acc[4][4];
#pragma unroll
    for (int i = 0; i < 4; ++i)
#pragma unroll
        for (int j = 0; j < 4; ++j) acc[i][j] = (f32x4){0.f, 0.f, 0.f, 0.f};

    for (int k0 = 0; k0 < K; k0 += 64) {
#pragma unroll
        for (int i = 0; i < 4; ++i) {
            int ci  = (i * 4 + wave) * 64 + lane;
            int row = ci >> 3, c = (ci & 7) * 8;
            gl_lds16(&A[(size_t)(m0 + row) * K + k0 + c],
                     (char*)As + (i * 4 + wave) * 1024);
            gl_lds16(&Bt[(size_t)(n0 + row) * K + k0 + c],
                     (char*)Bs + (i * 4 + wave) * 1024);
        }
        __syncthreads();
#pragma unroll
        for (int ks = 0; ks < 64; ks += 32) {
            bf16x8 a[4], b[4];
#pragma unroll
            for (int i = 0; i < 4; ++i)
                a[i] = *(const bf16x8*)&As[(wm + i * 16 + l15) * 64 + ks + quad * 8];
#pragma unroll
            for (int j = 0; j < 4; ++j)
                b[j] = *(const bf16x8*)&Bs[(wn + j * 16 + l15) * 64 + ks + quad * 8];
#pragma unroll
            for (int i = 0; i < 4; ++i)
#pragma unroll
                for (int j = 0; j < 4; ++j)
                    acc[i][j] = MFMA16(a[i], b[j], acc[i][j]);
        }
        __syncthreads();
    }
#pragma unroll
    for (int i = 0; i < 4; ++i)
#pragma unroll
        for (int j = 0; j < 4; ++j)
#pragma unroll
            for (int r = 0; r < 4; ++r) {
                int row = m0 + wm + i * 16 + quad * 4 + r;
                int col = n0 + wn + j * 16 + l15;
                if (BF16OUT)
                    ((u16*)Cout)[(size_t)row * N + col] = f2bf(acc[i][j][r]);
                else
                    ((float*)Cout)[(size_t)row * N + col] = acc[i][j][r];
            }
}

// ---------------- attention v3 ----------------
// 128 q-rows per block (4 waves x 2 strips of 16 q). Two-pass softmax.
// Pass 1: per-lane online (m,l), single butterfly merge at end (no per-kt shfl).
// Pass 2: sigma-reordered PV slot dim -> Pa written as ds_write_b64.
// LDS 48 KB: QP/Pa [128][64] 16K | Ks dbuf 2x8K | Vt dbuf 2x8K.
__global__ __launch_bounds__(256) void attn_v3(
    const u16* __restrict__ qkv,     // [B*L][3*D] bf16
    const float* __restrict__ bias,  // [B][L]
    float* __restrict__ align_out,   // [B*H][Lk][Lq] fp32
    u16* __restrict__ ctx_out)       // [B*L][D] bf16
{
    __shared__ u16 smem[24576];
    u16* QP = smem;            // 16 KB: Q, later reused as Pa [128][64]
    u16* Ks = smem + 8192;     // 2 x 8 KB
    u16* Vt = smem + 16384;    // 2 x 8 KB

    const int tid  = threadIdx.x;
    const int lane = tid & 63, wave = tid >> 6;
    const int l15  = lane & 15, quad = lane >> 4;
    const int wq   = wave * 32;
    // bijective XCD swizzle: 512 blocks = 8 chunks of 64 (4 heads per chunk)
    const int bid = ((blockIdx.x & 7) << 6) | (blockIdx.x >> 3);
    const int bh = bid >> 4, qt = bid & 15;
    const int b  = bh >> 4, h = bh & 15;
    const int q0 = qt * 128;
    const u16* qbase = qkv + (size_t)b * LL * (3 * DD);
    const float scale = 0.125f;

    // ---- stage Q tile [128][64] (swizzled source -> linear LDS) ----
#pragma unroll
    for (int i = 0; i < 4; ++i) {
        int ci  = (i * 4 + wave) * 64 + lane;
        int row = ci >> 3, c = ci & 7;
        int cs  = c ^ ((row ^ (row >> 3)) & 7);
        gl_lds16(&qbase[(size_t)(q0 + row) * (3 * DD) + h * DHD + cs * 8],
                 (char*)QP + (i * 4 + wave) * 1024);
    }
    __syncthreads();
    bf16x8 aq[2][2];
#pragma unroll
    for (int s = 0; s < 2; ++s) {
        aq[s][0] = *(const bf16x8*)((const char*)QP + swz(wq + s * 16 + l15, quad * 8));
        aq[s][1] = *(const bf16x8*)((const char*)QP + swz(wq + s * 16 + l15, 32 + quad * 8));
    }

    auto stageK = [&](int kt, int bi) {
#pragma unroll
        for (int i = 0; i < 2; ++i) {
            int ci  = (i * 4 + wave) * 64 + lane;
            int row = ci >> 3, c = ci & 7;
            int cs  = c ^ ((row ^ (row >> 3)) & 7);
            gl_lds16(&qbase[(size_t)(kt * 64 + row) * (3 * DD) + DD + h * DHD + cs * 8],
                     (char*)(Ks + bi * 4096) + (i * 4 + wave) * 1024);
        }
    };

    float m_[2][4], l_[2][4];
#pragma unroll
    for (int s = 0; s < 2; ++s)
#pragma unroll
        for (int r = 0; r < 4; ++r) { m_[s][r] = -3e38f; l_[s][r] = 0.f; }

    // ---------- pass 1: per-lane online max/sumexp (no per-kt shuffles) ----------
    stageK(0, 0);
    __syncthreads();
    for (int kt = 0; kt < 32; ++kt) {
        const int cur = kt & 1;
        if (kt < 31) stageK(kt + 1, cur ^ 1);
        const char* kb = (const char*)(Ks + cur * 4096);
        float Sv[2][4][4];
#pragma unroll
        for (int j = 0; j < 4; ++j) {
            bf16x8 bk0 = *(const bf16x8*)(kb + swz(j * 16 + l15, quad * 8));
            bf16x8 bk1 = *(const bf16x8*)(kb + swz(j * 16 + l15, 32 + quad * 8));
            float bv = bias[b * LL + kt * 64 + j * 16 + l15];
#pragma unroll
            for (int s = 0; s < 2; ++s) {
                f32x4 sa = (f32x4){0.f, 0.f, 0.f, 0.f};
                sa = MFMA16(aq[s][0], bk0, sa);
                sa = MFMA16(aq[s][1], bk1, sa);
#pragma unroll
                for (int r = 0; r < 4; ++r) Sv[s][j][r] = sa[r] * scale + bv;
            }
        }
#pragma unroll
        for (int s = 0; s < 2; ++s)
#pragma unroll
            for (int r = 0; r < 4; ++r) {
                float tm = fmaxf(fmaxf(Sv[s][0][r], Sv[s][1][r]),
                                 fmaxf(Sv[s][2][r], Sv[s][3][r]));
                if (tm > m_[s][r]) {          // defer-rescale (T13-style)
                    l_[s][r] *= __expf(m_[s][r] - tm);
                    m_[s][r] = tm;
                }
                l_[s][r] += __expf(Sv[s][0][r] - m_[s][r]) + __expf(Sv[s][1][r] - m_[s][r]) +
                            __expf(Sv[s][2][r] - m_[s][r]) + __expf(Sv[s][3][r] - m_[s][r]);
            }
        __syncthreads();
    }

    // single cross-lane merge over the 16 key-residue classes (l15 dim)
    float rl[2][4];
#pragma unroll
    for (int s = 0; s < 2; ++s)
#pragma unroll
        for (int r = 0; r < 4; ++r) {
            float mv = m_[s][r], lv = l_[s][r];
#pragma unroll
            for (int off = 1; off < 16; off <<= 1) {
                float om = __shfl_xor(mv, off);
                float ol = __shfl_xor(lv, off);
                float mn = fmaxf(mv, om);
                lv = lv * __expf(mv - mn) + ol * __expf(om - mn);
                mv = mn;
            }
            m_[s][r] = mv;
            rl[s][r] = 1.f / lv;
        }

    f32x4 ctx[2][4];
#pragma unroll
    for (int s = 0; s < 2; ++s)
#pragma unroll
        for (int j = 0; j < 4; ++j) ctx[s][j] = (f32x4){0.f, 0.f, 0.f, 0.f};

    u16* Pa = QP;  // reuse Q LDS as P buffer [128 q][64 slots], sigma slot order

    // V reg-staging; sigma slot: p(key) = (key&15)*4 + (key>>4)
    const int vr0 = tid >> 3, vs0 = tid & 7;
    const int vr1 = 32 + (tid >> 3), vs1 = tid & 7;
    const int p0c = (vr0 & 15) * 4 + (vr0 >> 4);
    const int p1c = (vr1 & 15) * 4 + (vr1 >> 4);
    const u16* vbase = qbase + 2 * DD + h * DHD;
    bf16x8 vv0, vv1;
    auto loadV = [&](int kt) {
        vv0 = *(const bf16x8*)&vbase[(size_t)(kt * 64 + vr0) * (3 * DD) + vs0 * 8];
        vv1 = *(const bf16x8*)&vbase[(size_t)(kt * 64 + vr1) * (3 * DD) + vs1 * 8];
    };
    auto writeV = [&](int bi) {
        u16* vb = Vt + bi * 4096;
#pragma unroll
        for (int e = 0; e < 8; ++e)
            *(u16*)((char*)vb + swz(vs0 * 8 + e, p0c)) = (u16)vv0[e];
#pragma unroll
        for (int e = 0; e < 8; ++e)
            *(u16*)((char*)vb + swz(vs1 * 8 + e, p1c)) = (u16)vv1[e];
    };

    // ---------- pass 2 ----------
    stageK(0, 0);
    loadV(0);
    writeV(0);
    __syncthreads();
    for (int kt = 0; kt < 32; ++kt) {
        const int cur = kt & 1;
        if (kt < 31) { stageK(kt + 1, cur ^ 1); loadV(kt + 1); }

        const char* kb = (const char*)(Ks + cur * 4096);
        float Sv[2][4][4];
#pragma unroll
        for (int j = 0; j < 4; ++j) {
            bf16x8 bk0 = *(const bf16x8*)(kb + swz(j * 16 + l15, quad * 8));
            bf16x8 bk1 = *(const bf16x8*)(kb + swz(j * 16 + l15, 32 + quad * 8));
            float bv = bias[b * LL + kt * 64 + j * 16 + l15];
#pragma unroll
            for (int s = 0; s < 2; ++s) {
                f32x4 sa = (f32x4){0.f, 0.f, 0.f, 0.f};
                sa = MFMA16(aq[s][0], bk0, sa);
                sa = MFMA16(aq[s][1], bk1, sa);
#pragma unroll
                for (int r = 0; r < 4; ++r) Sv[s][j][r] = sa[r] * scale + bv;
            }
        }
        // P: direct align stores (f32x4 along q) + Pa b64 writes (sigma order)
#pragma unroll
        for (int s = 0; s < 2; ++s) {
            float p[4][4];
#pragma unroll
            for (int j = 0; j < 4; ++j) {
                f32x4 pv;
#pragma unroll
                for (int r = 0; r < 4; ++r) {
                    pv[r] = __expf(Sv[s][j][r] - m_[s][r]) * rl[s][r];
                    p[j][r] = pv[r];
                }
                *(f32x4*)&align_out[((size_t)bh * LL + kt * 64 + j * 16 + l15) * LL +
                                    q0 + wq + s * 16 + quad * 4] = pv;
            }
#pragma unroll
            for (int r = 0; r < 4; ++r) {
                ull w = pack4(p[0][r], p[1][r], p[2][r], p[3][r]);
                int row = wq + s * 16 + quad * 4 + r;
                int k7 = (row ^ (row >> 3)) & 7;
                *(ull*)((char*)Pa + (row << 7) + ((((l15 >> 1) << 4) ^ (k7 << 4))) +
                        ((l15 & 1) << 3)) = w;
            }
        }
        __syncthreads();   // Pa visible; Vt[cur] visible since prev barrier
#pragma unroll
        for (int ks = 0; ks < 64; ks += 32) {
            const char* vb = (const char*)(Vt + cur * 4096);
            bf16x8 ap0 = *(const bf16x8*)((const char*)Pa + swz(wq + l15, ks + quad * 8));
            bf16x8 ap1 = *(const bf16x8*)((const char*)Pa + swz(wq + 16 + l15, ks + quad * 8));
#pragma unroll
            for (int j = 0; j < 4; ++j) {
                bf16x8 bvv = *(const bf16x8*)(vb + swz(j * 16 + l15, ks + quad * 8));
                ctx[0][j] = MFMA16(ap0, bvv, ctx[0][j]);
                ctx[1][j] = MFMA16(ap1, bvv, ctx[1][j]);
            }
        }
        if (kt < 31) writeV(cur ^ 1);
        __syncthreads();
    }

    // ctx -> bf16 [B*L][D]
#pragma unroll
    for (int s = 0; s < 2; ++s)
#pragma unroll
        for (int j = 0; j < 4; ++j)
#pragma unroll
            for (int r = 0; r < 4; ++r) {
                int ql = wq + s * 16 + quad * 4 + r;
                int dv = j * 16 + l15;
                ctx_out[(size_t)(b * LL + q0 + ql) * DD + h * DHD + dv] = f2bf(ctx[s][j][r]);
            }
}

extern "C" void kernel_launch(void* const* d_in, const int* in_sizes, int n_in,
                              void* d_out, int out_size, void* d_ws, size_t ws_size,
                              hipStream_t stream) {
    const float* queries = (const float*)d_in[0];
    const float* bias    = (const float*)d_in[1];
    const float* w_qkv   = (const float*)d_in[2];
    const float* w_o     = (const float*)d_in[3];

    float* out_p   = (float*)d_out;
    float* align_p = out_p + (size_t)BB * LL * DD;

    u16* qbf   = (u16*)d_ws;                          // [4096][1024] bf16
    u16* wqkT  = qbf + (size_t)BB * LL * DD;          // [3072][1024] bf16
    u16* woT   = wqkT + (size_t)(3 * DD) * DD;        // [1024][1024] bf16
    u16* qkvbf = woT + (size_t)DD * DD;               // [4096][3072] bf16
    u16* ctxbf = qkvbf + (size_t)BB * LL * 3 * DD;    // [4096][1024] bf16

    to_bf16<<<(BB * LL * DD / 4 + 255) / 256, 256, 0, stream>>>(queries, qbf, BB * LL * DD / 4);
    transpose_bf16<<<dim3(3 * DD / 32, DD / 32), 256, 0, stream>>>(w_qkv, wqkT, DD, 3 * DD);
    transpose_bf16<<<dim3(DD / 32, DD / 32), 256, 0, stream>>>(w_o, woT, DD, DD);

    gemm_bt<1><<<dim3(3 * DD / 128, BB * LL / 128), 256, 0, stream>>>(
        qbf, wqkT, qkvbf, BB * LL, 3 * DD, DD);

    attn_v3<<<dim3(BB * HH * (LL / 128)), 256, 0, stream>>>(qkvbf, bias, align_p, ctxbf);

    gemm_bt<0><<<dim3(DD / 128, BB * LL / 128), 256, 0, stream>>>(
        ctxbf, woT, out_p, BB * LL, DD, DD);
}